// Round 10
// baseline (224.602 us; speedup 1.0000x reference)
//
#include <hip/hip_runtime.h>

typedef __bf16 bf16;
typedef __bf16 bf16x4 __attribute__((ext_vector_type(4)));
typedef __bf16 bf16x8 __attribute__((ext_vector_type(8)));
typedef float  f32x4  __attribute__((ext_vector_type(4)));

// ---------------------------------------------------------------- helpers
__device__ __forceinline__ void gld16(const void* g, void* l) {
  __builtin_amdgcn_global_load_lds(
      (const __attribute__((address_space(1))) void*)g,
      (__attribute__((address_space(3))) void*)l, 16, 0, 0);
}

// ---------------------------------------------------------------- fused fp32 -> bf16 (all three tensors, one launch)
__global__ void f2bf_all(const float* __restrict__ x, bf16* __restrict__ xo,
                         const float* __restrict__ w1, bf16* __restrict__ w1o,
                         const float* __restrict__ w2, bf16* __restrict__ w2o) {
  int i = blockIdx.x * blockDim.x + threadIdx.x;   // grid covers 2097152 float4s
  const float* in; bf16* out; int idx;
  if (i < 1048576)      { in = x;  out = xo;  idx = i; }
  else if (i < 1835008) { in = w1; out = w1o; idx = i - 1048576; }
  else                  { in = w2; out = w2o; idx = i - 1835008; }
  float4 v = reinterpret_cast<const float4*>(in)[idx];
  bf16x4 o = { (bf16)v.x, (bf16)v.y, (bf16)v.z, (bf16)v.w };
  reinterpret_cast<bf16x4*>(out)[idx] = o;
}

// ---------------------------------------------------------------- GEMM: C[M,N] = A[M,K] * B[N,K]^T + bias
// MODE 0 (BN=128): QKV epilogue. Q/K scatter to [sec][B*H][S][64] (q scaled
//   by 0.125*log2e); V section writes V^T into the V-third of QKV as
//   [B*H][64][2048] (4 consecutive s at fixed d = one bf16x4 store).
// MODE 1 (BN=64): out-proj epilogue -> fp32 C += bias
template<int MODE, int BN>
__global__ __launch_bounds__(256)
void gemm_bt(const bf16* __restrict__ A, const bf16* __restrict__ B,
             const float* __restrict__ bias, void* __restrict__ Cout,
             int K, int N) {
  __shared__ bf16 As[128 * 64];
  __shared__ bf16 Bs[BN * 64];
  const int tid  = threadIdx.x;
  const int wave = tid >> 6, lane = tid & 63;
  const int quad = lane >> 4, l16 = lane & 15;
  const int bm = blockIdx.x * 128, bn = blockIdx.y * BN;
  constexpr int NI  = (BN == 128) ? 4 : 2;
  constexpr int BCH = BN / 32;
  const int wr = (BN == 128) ? (wave >> 1) * 64 : wave * 32;
  const int wc = (BN == 128) ? (wave & 1) * 64 : 0;
  const int arow = lane >> 3;
  const int acol = (lane & 7) * 8;

  f32x4 acc[NI][4] = {};

  const bf16* Ab = A + (size_t)bm * K;
  const bf16* Bb = B + (size_t)bn * K;

  for (int k0 = 0; k0 < K; k0 += 64) {
#pragma unroll
    for (int i = 0; i < 4; ++i) {
      int c = wave * 4 + i;
      gld16(Ab + (size_t)(c * 8 + arow) * K + k0 + acol, As + c * 512);
    }
#pragma unroll
    for (int i = 0; i < BCH; ++i) {
      int c = wave * BCH + i;
      gld16(Bb + (size_t)(c * 8 + arow) * K + k0 + acol, Bs + c * 512);
    }
    __syncthreads();
#pragma unroll
    for (int kk = 0; kk < 64; kk += 32) {
      bf16x8 af[NI], bfr[4];
#pragma unroll
      for (int i = 0; i < NI; ++i)
        af[i]  = *(const bf16x8*)(As + (wr + i * 16 + l16) * 64 + kk + quad * 8);
#pragma unroll
      for (int j = 0; j < 4; ++j)
        bfr[j] = *(const bf16x8*)(Bs + (wc + j * 16 + l16) * 64 + kk + quad * 8);
#pragma unroll
      for (int i = 0; i < NI; ++i)
#pragma unroll
        for (int j = 0; j < 4; ++j)
          acc[i][j] = __builtin_amdgcn_mfma_f32_16x16x32_bf16(af[i], bfr[j], acc[i][j], 0, 0, 0);
    }
    __syncthreads();
  }

  if constexpr (MODE == 0) {
    bf16* Q = (bf16*)Cout;  // [3][32][2048][64]; V-third holds V^T [32][64][2048]
#pragma unroll
    for (int j = 0; j < 4; ++j) {
      int col = bn + wc + j * 16 + l16;
      float bv  = bias[col];
      int sec = col >> 10, rem = col & 1023;
      int h = rem >> 6, d = rem & 63;
      if (sec < 2) {
        float scl = (sec == 0) ? 0.125f * 1.44269504f : 1.0f;
#pragma unroll
        for (int i = 0; i < NI; ++i) {
#pragma unroll
          for (int r = 0; r < 4; ++r) {
            int row = bm + wr + i * 16 + quad * 4 + r;
            int b = row >> 11, si = row & 2047;
            float v = (acc[i][j][r] + bv) * scl;
            Q[(((size_t)sec * 32 + b * 16 + h) * 2048 + si) * 64 + d] = (bf16)v;
          }
        }
      } else {
#pragma unroll
        for (int i = 0; i < NI; ++i) {
          int row0 = bm + wr + i * 16 + quad * 4;
          int b = row0 >> 11, si = row0 & 2047;
          bf16x4 pk = { (bf16)(acc[i][j][0] + bv), (bf16)(acc[i][j][1] + bv),
                        (bf16)(acc[i][j][2] + bv), (bf16)(acc[i][j][3] + bv) };
          *(bf16x4*)(Q + (size_t)2 * 4194304 +
                     ((size_t)(b * 16 + h) * 64 + d) * 2048 + si) = pk;
        }
      }
    }
  } else {
    float* C = (float*)Cout;
#pragma unroll
    for (int j = 0; j < 4; ++j) {
      int col = bn + wc + j * 16 + l16;
      float bv = bias[col];
#pragma unroll
      for (int i = 0; i < NI; ++i)
#pragma unroll
        for (int r = 0; r < 4; ++r) {
          int row = bm + wr + i * 16 + quad * 4 + r;
          C[(size_t)row * N + col] = acc[i][j][r] + bv;
        }
    }
  }
}

// ---------------------------------------------------------------- flash attention v9: occupancy via small blocks
// 128-thread blocks (2 waves), 64 q-rows/block, 32 q-rows/wave (unchanged
// per-wave arithmetic intensity — R5/R7's mistake was shrinking this).
// Grid 32x32 = 1024 blocks, bh fastest -> blk%8 = bh%8 (XCD-local K/V, R9:
// FETCH 69.7->12.3 MB). K-tiles of 64 keys in a SINGLE 9216 B LDS buffer;
// per-wave Ps 8704 B x2 -> total LDS 26624 B -> 6 blocks/CU = 12 waves/CU
// (3/SIMD, 1.5x R9's 2/SIMD which capped all prior structures at ~78 us).
// 2 barriers/tile over a 2-wave group (cheap); K staging regs->LDS overlaps
// exp/PV. S^T-form QK (lane holds 4 consecutive k-cols); V frags direct
// from global V^T. Q pre-scaled 0.125*log2e -> bare exp2; deferred row sums.
__global__ __launch_bounds__(128, 3)
void attn_kernel(const bf16* __restrict__ QKV, const bf16* __restrict__ Vt,
                 bf16* __restrict__ O) {
  __shared__ bf16 Ks[64 * 72];         // 9216 B, single buffer
  __shared__ bf16 Ps[2][32 * 136];     // 17408 B

  const int bh = blockIdx.x;               // fast dim -> XCD locality
  const int q0 = blockIdx.y * 64;
  const bf16* Qg = QKV + ((size_t)bh * 2048 + q0) * 64;
  const bf16* Kg = QKV + (size_t)32 * 2048 * 64 + (size_t)bh * 2048 * 64;
  const bf16* Vg = Vt + (size_t)bh * 64 * 2048;

  const int tid  = threadIdx.x;
  const int wave = tid >> 6, lane = tid & 63;
  const int quad = lane >> 4, l16 = lane & 15;
  const int srow = tid >> 3;            // 0..15 staging row base
  const int scol = (tid & 7) * 8;       // 0..56 staging col
  bf16* Pw = &Ps[wave][0];

  // Q fragments in registers (B-operand), reused across all 32 K-tiles
  bf16x8 aq[2][2];
#pragma unroll
  for (int i = 0; i < 2; ++i)
#pragma unroll
    for (int kh = 0; kh < 2; ++kh)
      aq[i][kh] = *(const bf16x8*)(Qg + (size_t)(wave * 32 + i * 16 + l16) * 64 +
                                   kh * 32 + quad * 8);

  // preload K tile 0 (64 rows x 64 cols; 4 chunks of 16 rows per thread)
  {
    bf16x8 kreg[4];
#pragma unroll
    for (int c = 0; c < 4; ++c)
      kreg[c] = *(const bf16x8*)(Kg + (size_t)(c * 16 + srow) * 64 + scol);
#pragma unroll
    for (int c = 0; c < 4; ++c)
      *(bf16x8*)(&Ks[(c * 16 + srow) * 72 + scol]) = kreg[c];
  }
  __syncthreads();

  float rs[2] = {0.f, 0.f};             // per-lane partial row sums (qrow = i*16+l16)
  f32x4 o[2][4] = {};

  for (int kt = 0; kt < 32; ++kt) {
    // prefetch next K tile to regs (in flight across QK + barrier)
    bf16x8 kreg[4];
    if (kt < 31) {
#pragma unroll
      for (int c = 0; c < 4; ++c)
        kreg[c] = *(const bf16x8*)(Kg + (size_t)((kt + 1) * 64 + c * 16 + srow) * 64 + scol);
    }
    // prefetch V fragments for this tile (consumed after QK+exp)
    bf16x8 bv[2][4];
#pragma unroll
    for (int kk = 0; kk < 2; ++kk)
#pragma unroll
      for (int oj = 0; oj < 4; ++oj)
        bv[kk][oj] = *(const bf16x8*)(Vg + (size_t)(oj * 16 + l16) * 2048 +
                                      kt * 64 + kk * 32 + quad * 8);

    // ---- S^T = K Q^T : lane holds S[qrow=l16][kcol=ni*16+quad*4+r]
    f32x4 s[2][4] = {};
#pragma unroll
    for (int kh = 0; kh < 2; ++kh) {
#pragma unroll
      for (int ni = 0; ni < 4; ++ni) {
        bf16x8 bk = *(const bf16x8*)(&Ks[(ni * 16 + l16) * 72 + kh * 32 + quad * 8]);
        s[0][ni] = __builtin_amdgcn_mfma_f32_16x16x32_bf16(bk, aq[0][kh], s[0][ni], 0, 0, 0);
        s[1][ni] = __builtin_amdgcn_mfma_f32_16x16x32_bf16(bk, aq[1][kh], s[1][ni], 0, 0, 0);
      }
    }

    __syncthreads();   // both waves done reading Ks for tile kt

    // overwrite Ks with tile kt+1 (overlaps exp/PV below)
    if (kt < 31) {
#pragma unroll
      for (int c = 0; c < 4; ++c)
        *(bf16x8*)(&Ks[(c * 16 + srow) * 72 + scol]) = kreg[c];
    }

    // ---- P = exp2(S): 4 consecutive kcols/lane -> one b64 LDS write each
#pragma unroll
    for (int i = 0; i < 2; ++i)
#pragma unroll
      for (int ni = 0; ni < 4; ++ni) {
        float p0 = __builtin_amdgcn_exp2f(s[i][ni][0]);
        float p1 = __builtin_amdgcn_exp2f(s[i][ni][1]);
        float p2 = __builtin_amdgcn_exp2f(s[i][ni][2]);
        float p3 = __builtin_amdgcn_exp2f(s[i][ni][3]);
        rs[i] += (p0 + p1) + (p2 + p3);
        bf16x4 pk = { (bf16)p0, (bf16)p1, (bf16)p2, (bf16)p3 };
        *(bf16x4*)(Pw + (i * 16 + l16) * 136 + ni * 16 + quad * 4) = pk;
      }

    // ---- O += P V  (per-wave Ps; lgkmcnt orders write->read, no barrier)
#pragma unroll
    for (int kk = 0; kk < 2; ++kk) {
#pragma unroll
      for (int i = 0; i < 2; ++i) {
        bf16x8 ap = *(const bf16x8*)(Pw + (i * 16 + l16) * 136 + kk * 32 + quad * 8);
#pragma unroll
        for (int oj = 0; oj < 4; ++oj)
          o[i][oj] = __builtin_amdgcn_mfma_f32_16x16x32_bf16(ap, bv[kk][oj], o[i][oj], 0, 0, 0);
      }
    }

    __syncthreads();   // Ks writes for kt+1 visible before next QK
  }

  // ---- finalize row sums: quads hold partials for row l16
#pragma unroll
  for (int i = 0; i < 2; ++i) {
    rs[i] += __shfl_xor(rs[i], 16);
    rs[i] += __shfl_xor(rs[i], 32);
  }

  // ---- epilogue: redistribute 1/l to C-layout rows, write bf16
  const int b = bh >> 4, h = bh & 15;
#pragma unroll
  for (int i = 0; i < 2; ++i)
#pragma unroll
    for (int r = 0; r < 4; ++r) {
      float lsum = __shfl(rs[i], quad * 4 + r);   // sum for row quad*4+r (at lane l16=row)
      float inv = 1.0f / lsum;
      int row = q0 + wave * 32 + i * 16 + quad * 4 + r;
#pragma unroll
      for (int oj = 0; oj < 4; ++oj)
        O[((size_t)(b * 2048 + row)) * 1024 + h * 64 + oj * 16 + l16] =
            (bf16)(o[i][oj][r] * inv);
    }
}

// ---------------------------------------------------------------- launch
extern "C" void kernel_launch(void* const* d_in, const int* in_sizes, int n_in,
                              void* d_out, int out_size, void* d_ws, size_t ws_size,
                              hipStream_t stream) {
  const float* x      = (const float*)d_in[0];   // [2,2048,1024]
  const float* qkv_w  = (const float*)d_in[1];   // [3072,1024]
  const float* qkv_b  = (const float*)d_in[2];   // [3072]
  const float* out_w  = (const float*)d_in[3];   // [1024,1024]
  const float* out_b  = (const float*)d_in[4];   // [1024]
  float* out = (float*)d_out;                    // [2,2048,1024] fp32

  char* ws = (char*)d_ws;
  bf16* Xb   = (bf16*)(ws);                      // 8 MB
  bf16* Wqkv = (bf16*)(ws + 8388608);            // 6 MB
  bf16* Wout = (bf16*)(ws + 14680064);           // 2 MB
  bf16* QKV  = (bf16*)(ws + 16777216);           // 24 MB: [Q][K] + V^T third
  bf16* At   = (bf16*)(ws + 41943040);           // 8 MB attn output [B,S,1024]
  bf16* VtP  = QKV + (size_t)2 * 32 * 2048 * 64; // V^T [32][64][2048]

  f2bf_all<<<8192, 256, 0, stream>>>(x, Xb, qkv_w, Wqkv, out_w, Wout);

  gemm_bt<0, 128><<<dim3(32, 24), 256, 0, stream>>>(Xb, Wqkv, qkv_b, (void*)QKV, 1024, 3072);

  // grid (bh, q_tile): blk%8 = bh%8 -> per-head XCD locality; 1024 blocks
  attn_kernel<<<dim3(32, 32), 128, 0, stream>>>(QKV, VtP, At);

  gemm_bt<1, 64><<<dim3(32, 16), 256, 0, stream>>>(At, Wout, out_b, (void*)out, 1024, 1024);
}